// Round 14
// baseline (17478.947 us; speedup 1.0000x reference)
//
#include <hip/hip_runtime.h>
#include <stdint.h>

// LSTMModel: 4-layer LSTM (B=256,T=512,H=256,Din=28) + sigmoid proj (21)
// R13: decomposition flip. WG = (layer, 16 batch rows); recurrence is
// WG-LOCAL (no cross-WG sync on the critical path). Weights streamed from
// L2 every step (plain loads, 1MB/layer, XCD-resident). Feed-forward h +
// back-pressure are the only cross-WG edges: single-writer single-reader
// flags, plain relaxed stores. 64 WGs x 512 threads.

#define B 256
#define T 512
#define H 256
#define DIN 28
#define NWG 64
#define OUTD 21

typedef __attribute__((ext_vector_type(8))) __bf16 bf16x8;
typedef __attribute__((ext_vector_type(4))) float f32x4;
typedef unsigned long long u64;

// ---- workspace layout (bytes) ----
#define WS_FPROD 0ull                                  // [l*16+bs][512] u32 = 128 KB
#define WS_FCONS 131072ull                             // same, consumer progress
#define WS_HFF   262144ull                             // [l][slot4][256][256] bf16 = 2 MB
#define WS_XBF   (WS_HFF + 4ull*4*B*H*2)               // x bf16 [b][t][32] = 8 MB
#define WS_WCOMB (WS_XBF + (u64)B*T*32*2)              // [l][1024][512] bf16 = 4 MB
#define WS_BIAS  (WS_WCOMB + 4ull*1024*512*2)          // f32 [l][1024]
#define WS_ZERO  262144ull                             // memset: both flag arrays

__device__ __forceinline__ unsigned short f2bf(float f) {
  unsigned u = __builtin_bit_cast(unsigned, f);
  u += 0x7fffu + ((u >> 16) & 1u);
  return (unsigned short)(u >> 16);
}
__device__ __forceinline__ float bf2f(unsigned short v) {
  return __builtin_bit_cast(float, (unsigned)v << 16);
}
__device__ __forceinline__ float sigf(float x) { return 1.f / (1.f + __expf(-x)); }
__device__ __forceinline__ float tanhfast(float x) {
  float e = __expf(2.f * x);
  return 1.f - 2.f / (e + 1.f);
}
__device__ __forceinline__ bf16x8 ldb8(const void* p) { return *(const bf16x8*)p; }
__device__ __forceinline__ u64 ldq(const u64* p) {
  return __hip_atomic_load(p, __ATOMIC_RELAXED, __HIP_MEMORY_SCOPE_AGENT);
}
__device__ __forceinline__ void stq(void* p, u64 v) {
  __hip_atomic_store((u64*)p, v, __ATOMIC_RELAXED, __HIP_MEMORY_SCOPE_AGENT);
}
__device__ __forceinline__ unsigned ldflag(const unsigned* f) {
  return __hip_atomic_load(f, __ATOMIC_RELAXED, __HIP_MEMORY_SCOPE_AGENT);
}
__device__ __forceinline__ void stflag(unsigned* f, unsigned v) {
  __hip_atomic_store(f, v, __ATOMIC_RELAXED, __HIP_MEMORY_SCOPE_AGENT);
}

// ---------------- prep kernels ----------------
__global__ void prep_x(const float* __restrict__ x, unsigned short* __restrict__ xbf) {
  int tot = B * T * 32;
  for (int idx = blockIdx.x * blockDim.x + threadIdx.x; idx < tot;
       idx += gridDim.x * blockDim.x) {
    int kk = idx & 31;
    int bt = idx >> 5;
    float v = (kk < DIN) ? x[(size_t)bt * DIN + kk] : 0.f;
    xbf[idx] = f2bf(v);
  }
}

// combined weights: wcomb[l][n'=4j+g][k]  k<256: W_ih (l0: k<32 x-block, rest 0),
// k>=256: W_hh. bias = b_ih + b_hh, reordered.
__global__ void prep_wc(const float* __restrict__ wih0, const float* __restrict__ wihrest,
                        const float* __restrict__ whh, const float* __restrict__ bih,
                        const float* __restrict__ bhh, unsigned short* __restrict__ wcomb,
                        float* __restrict__ biasr) {
  const int W = 4 * 1024 * 512, Bt = 4 * 1024;
  int tot = W + Bt;
  for (int idx = blockIdx.x * blockDim.x + threadIdx.x; idx < tot;
       idx += gridDim.x * blockDim.x) {
    if (idx < W) {
      int k = idx & 511, r = idx >> 9, np = r & 1023, l = r >> 10;
      int g = np & 3, j = np >> 2;
      float v;
      if (k >= 256) {
        v = whh[((size_t)l * 1024 + g * 256 + j) * 256 + (k - 256)];
      } else if (l == 0) {
        v = (k < DIN) ? wih0[(size_t)(g * 256 + j) * DIN + k] : 0.f;
      } else {
        v = wihrest[((size_t)(l - 1) * 1024 + g * 256 + j) * 256 + k];
      }
      wcomb[idx] = f2bf(v);
    } else {
      int i = idx - W;
      int np = i & 1023, l = i >> 10, g = np & 3, j = np >> 2;
      biasr[i] = bih[l * 1024 + g * 256 + j] + bhh[l * 1024 + g * 256 + j];
    }
  }
}

// ---------------- main persistent kernel ----------------
__launch_bounds__(512, 2)
__global__ void lstm_main(const unsigned short* __restrict__ xbf,
                          const unsigned short* __restrict__ wcomb,
                          const float* __restrict__ biasr,
                          const float* __restrict__ Wout, const float* __restrict__ bout,
                          unsigned short* __restrict__ hff, unsigned* __restrict__ fprod,
                          unsigned* __restrict__ fcons, float* __restrict__ out) {
  __shared__ unsigned char panel[16 * 1024];   // A panel: 16 b-rows x 1KB [prev|rec], swizzled
  __shared__ float gl[1024 * 20];              // gates [n'][20] (b cols 0..15, pad)

  const int tid = threadIdx.x;
  const int lane = tid & 63;
  const int wv = tid >> 6;                     // wave 0..7
  const int bid = blockIdx.x;
  const int layer = bid & 3;
  const int bs = bid >> 2;                     // 0..15
  const int b0 = bs * 16;

  const int r16 = lane & 15;                   // frag row (b for A, n' for B)
  const int ksub = lane >> 4;                  // 0..3 (8-elem K sub-chunk)
  const int nw0 = wv * 128;                    // wave's n' base

  const unsigned short* wl = wcomb + (size_t)layer * 1024 * 512;

  float bv[8];
#pragma unroll
  for (int nt = 0; nt < 8; ++nt)
    bv[nt] = biasr[layer * 1024 + nw0 + nt * 16 + r16];

  unsigned* fp_own = fprod + (size_t)(layer * 16 + bs) * 512;
  const unsigned* fp_up = (layer > 0) ? fprod + (size_t)((layer - 1) * 16 + bs) * 512 : nullptr;
  unsigned* fc_own = fcons + (size_t)(layer * 16 + bs) * 512;
  const unsigned* fc_dn = (layer < 3) ? fcons + (size_t)((layer + 1) * 16 + bs) * 512 : nullptr;

  // act mapping: thread = (b = tid&15, jq = tid>>4), j = jq*8..+8
  const int ab = tid & 15;
  const int ajq = tid >> 4;
  float creg[8];
#pragma unroll
  for (int i = 0; i < 8; ++i) creg[i] = 0.f;

  // prev-h staging mapping: row = tid>>5 (0..15), col = tid&31 (16B units)
  const int prow = tid >> 5;
  const int pcol = tid & 31;

  for (int t = 0; t < T; ++t) {
    // ---- polls: single-writer single-reader flags, sleep-paced ----
    if (tid == 0) {
      if (fp_up) {
        while (ldflag(&fp_up[t]) == 0u) __builtin_amdgcn_s_sleep(1);
      }
      if (fc_dn && t >= 4) {
        while (ldflag(&fc_dn[t - 4]) == 0u) __builtin_amdgcn_s_sleep(1);
      }
    }
    __syncthreads();
    asm volatile("" ::: "memory");

    // ---- issue prev-input loads (hidden under rec pass) ----
    u64 pv0 = 0, pv1 = 0;
    if (layer == 0) {
      if (tid < 64) {
        const u64* s = (const u64*)(xbf + ((size_t)(b0 + (tid >> 2)) * T + t) * 32 + (tid & 3) * 8);
        pv0 = s[0];
        pv1 = s[1];
      }
    } else {
      const u64* s = (const u64*)(hff + (((size_t)(layer - 1) * 4 + (t & 3)) * B + (b0 + prow)) * H + pcol * 8);
      pv0 = ldq(s);
      pv1 = ldq(s + 1);
    }
    __builtin_amdgcn_sched_barrier(0);

    // ---- accumulators (bias init) ----
    f32x4 acc[8];
#pragma unroll
    for (int nt = 0; nt < 8; ++nt) acc[nt] = (f32x4){bv[nt], bv[nt], bv[nt], bv[nt]};

    // ---- rec pass: A from local LDS (written by act of t-1), B streamed from L2 ----
    if (t > 0) {
      bf16x8 arec[8];
#pragma unroll
      for (int kk = 0; kk < 8; ++kk)
        arec[kk] = *(const bf16x8*)(panel + r16 * 1024 + ((512 + kk * 64 + ksub * 16) ^ (r16 << 4)));
#pragma unroll
      for (int nt = 0; nt < 8; ++nt) {
        const unsigned short* wr = wl + (size_t)(nw0 + nt * 16 + r16) * 512 + 256 + ksub * 8;
        bf16x8 bb[8];
#pragma unroll
        for (int kk = 0; kk < 8; ++kk) bb[kk] = ldb8(wr + kk * 32);
#pragma unroll
        for (int kk = 0; kk < 8; ++kk)
          acc[nt] = __builtin_amdgcn_mfma_f32_16x16x32_bf16(arec[kk], bb[kk], acc[nt], 0, 0, 0);
      }
    }

    // ---- prev half: wait loads, write panel, barrier ----
    asm volatile("s_waitcnt vmcnt(0)" ::: "memory");
    if (layer == 0) {
      if (tid < 64) {
        int row = tid >> 2;
        uint4 v;
        ((u64*)&v)[0] = pv0;
        ((u64*)&v)[1] = pv1;
        *(uint4*)(panel + row * 1024 + (((tid & 3) * 16) ^ (row << 4))) = v;
      }
    } else {
      uint4 v;
      ((u64*)&v)[0] = pv0;
      ((u64*)&v)[1] = pv1;
      *(uint4*)(panel + prow * 1024 + ((pcol * 16) ^ (prow << 4))) = v;
    }
    __syncthreads();

    // ---- prev pass ----
    if (layer == 0) {
      bf16x8 a0 = *(const bf16x8*)(panel + r16 * 1024 + ((ksub * 16) ^ (r16 << 4)));
#pragma unroll
      for (int nt = 0; nt < 8; ++nt) {
        bf16x8 b0v = ldb8(wl + (size_t)(nw0 + nt * 16 + r16) * 512 + ksub * 8);
        acc[nt] = __builtin_amdgcn_mfma_f32_16x16x32_bf16(a0, b0v, acc[nt], 0, 0, 0);
      }
    } else {
      bf16x8 aprev[8];
#pragma unroll
      for (int kk = 0; kk < 8; ++kk)
        aprev[kk] = *(const bf16x8*)(panel + r16 * 1024 + ((kk * 64 + ksub * 16) ^ (r16 << 4)));
#pragma unroll
      for (int nt = 0; nt < 8; ++nt) {
        const unsigned short* wr = wl + (size_t)(nw0 + nt * 16 + r16) * 512 + ksub * 8;
        bf16x8 bb[8];
#pragma unroll
        for (int kk = 0; kk < 8; ++kk) bb[kk] = ldb8(wr + kk * 32);
#pragma unroll
        for (int kk = 0; kk < 8; ++kk)
          acc[nt] = __builtin_amdgcn_mfma_f32_16x16x32_bf16(aprev[kk], bb[kk], acc[nt], 0, 0, 0);
      }
    }

    // ---- scatter gates to LDS: gl[n'][20], b col = ksub*4 + reg ----
#pragma unroll
    for (int nt = 0; nt < 8; ++nt)
      *(f32x4*)&gl[(size_t)(nw0 + nt * 16 + r16) * 20 + ksub * 4] = acc[nt];
    __syncthreads();

    // ---- act + cell update + h stores ----
    {
      float hv[8];
#pragma unroll
      for (int i2 = 0; i2 < 8; ++i2) {
        int j = ajq * 8 + i2;
        float ip = gl[(4 * j + 0) * 20 + ab];
        float fp = gl[(4 * j + 1) * 20 + ab];
        float gp = gl[(4 * j + 2) * 20 + ab];
        float op = gl[(4 * j + 3) * 20 + ab];
        float ii = sigf(ip), ff = sigf(fp), gg = tanhfast(gp), oo = sigf(op);
        float cc = ff * creg[i2] + ii * gg;
        creg[i2] = cc;
        hv[i2] = oo * tanhfast(cc);
      }
      unsigned short hb[8];
#pragma unroll
      for (int i2 = 0; i2 < 8; ++i2) hb[i2] = f2bf(hv[i2]);
      u64 q0, q1;
      memcpy(&q0, &hb[0], 8);
      memcpy(&q1, &hb[4], 8);
      // local rec half for t+1 (all MFMA reads done: post-scatter barrier)
      uint4 v;
      ((u64*)&v)[0] = q0;
      ((u64*)&v)[1] = q1;
      *(uint4*)(panel + ab * 1024 + ((512 + ajq * 16) ^ (ab << 4))) = v;
      // feed-forward h for layer+1
      if (layer < 3) {
        u64* d = (u64*)(hff + (((size_t)layer * 4 + (t & 3)) * B + (b0 + ab)) * H + ajq * 8);
        stq(d, q0);
        stq(d + 1, q1);
      }
    }
    // drain ff stores, then publish flags (plain relaxed stores, single writer)
    asm volatile("s_waitcnt vmcnt(0)" ::: "memory");
    __syncthreads();
    if (tid == 0) {
      if (layer < 3) stflag(&fp_own[t], 1u);
      if (layer > 0) stflag(&fc_own[t], 1u);
    }
  }

  // ---- final projection (layer 3): h(T-1) is in local panel rec half ----
  if (layer == 3) {
    __syncthreads();
    if (tid < 16 * OUTD) {
      int o = tid % OUTD, b = tid / OUTD;
      const float* wr = Wout + (size_t)o * H;
      float sum = bout[o];
      for (int k = 0; k < H; ++k) {
        int off = 512 + k * 2;
        int sw = ((off & ~15) ^ (b << 4)) | (off & 15);
        unsigned short hvs = *(const unsigned short*)(panel + b * 1024 + sw);
        sum = fmaf(bf2f(hvs), wr[k], sum);
      }
      out[(b0 + b) * OUTD + o] = sigf(sum);
    }
  }
}

extern "C" void kernel_launch(void* const* d_in, const int* in_sizes, int n_in,
                              void* d_out, int out_size, void* d_ws, size_t ws_size,
                              hipStream_t stream) {
  const float* x = (const float*)d_in[0];
  const float* Wih0 = (const float*)d_in[1];
  const float* WihRest = (const float*)d_in[2];
  const float* Whh = (const float*)d_in[3];
  const float* bih = (const float*)d_in[4];
  const float* bhh = (const float*)d_in[5];
  const float* Wout = (const float*)d_in[6];
  const float* bout = (const float*)d_in[7];
  float* out = (float*)d_out;
  char* ws = (char*)d_ws;

  unsigned* fprod = (unsigned*)(ws + WS_FPROD);
  unsigned* fcons = (unsigned*)(ws + WS_FCONS);
  unsigned short* hff = (unsigned short*)(ws + WS_HFF);
  unsigned short* xbf = (unsigned short*)(ws + WS_XBF);
  unsigned short* wcomb = (unsigned short*)(ws + WS_WCOMB);
  float* biasr = (float*)(ws + WS_BIAS);

  hipMemsetAsync(ws, 0, (size_t)WS_ZERO, stream);
  prep_x<<<2048, 256, 0, stream>>>(x, xbf);
  prep_wc<<<2048, 256, 0, stream>>>(Wih0, WihRest, Whh, bih, bhh, wcomb, biasr);
  lstm_main<<<NWG, 512, 0, stream>>>(xbf, wcomb, biasr, Wout, bout, hff, fprod,
                                     fcons, out);
}